// Round 2
// baseline (277.025 us; speedup 1.0000x reference)
//
#include <hip/hip_runtime.h>
#include <hip/hip_bf16.h>
#include <stdint.h>

typedef __bf16 bf16;
typedef __bf16 bf16x8 __attribute__((ext_vector_type(8)));
typedef __bf16 bf16x4 __attribute__((ext_vector_type(4)));
typedef float  f32x4  __attribute__((ext_vector_type(4)));

#define MFMA16(A, B, C) __builtin_amdgcn_mfma_f32_16x16x32_bf16((A), (B), (C), 0, 0, 0)

static constexpr int Bsz = 4, Seq = 2048, Dm = 512, Hh = 8, Dh = 64;

__device__ __forceinline__ void g2l_16(void* lds, const void* gp) {
  __builtin_amdgcn_global_load_lds((__attribute__((address_space(1))) void*)gp,
                                   (__attribute__((address_space(3))) void*)lds, 16, 0, 0);
}

// ---------------- LayerNorm fp32 -> bf16, one wave per row (D=512) ----------------
__global__ __launch_bounds__(256) void ln_cast_kernel(
    const float* __restrict__ x, const float* __restrict__ g,
    const float* __restrict__ be, bf16* __restrict__ xn) {
  const int row  = blockIdx.x * 4 + (threadIdx.x >> 6);
  const int lane = threadIdx.x & 63;
  const f32x4* xr = (const f32x4*)(x + (size_t)row * Dm);
  f32x4 v0 = xr[lane];
  f32x4 v1 = xr[lane + 64];
  float s = (v0.x + v0.y + v0.z + v0.w) + (v1.x + v1.y + v1.z + v1.w);
#pragma unroll
  for (int off = 32; off > 0; off >>= 1) s += __shfl_xor(s, off);
  const float mu = s * (1.0f / Dm);
  f32x4 d0 = v0 - mu, d1 = v1 - mu;
  float q = d0.x * d0.x + d0.y * d0.y + d0.z * d0.z + d0.w * d0.w
          + d1.x * d1.x + d1.y * d1.y + d1.z * d1.z + d1.w * d1.w;
#pragma unroll
  for (int off = 32; off > 0; off >>= 1) q += __shfl_xor(q, off);
  const float rs = rsqrtf(q * (1.0f / Dm) + 1e-5f);
  const f32x4* gr = (const f32x4*)g;
  const f32x4* br = (const f32x4*)be;
  f32x4 g0 = gr[lane], g1 = gr[lane + 64];
  f32x4 b0 = br[lane], b1 = br[lane + 64];
  f32x4 y0 = d0 * rs * g0 + b0;
  f32x4 y1 = d1 * rs * g1 + b1;
  bf16x4 o0 = { (bf16)y0.x, (bf16)y0.y, (bf16)y0.z, (bf16)y0.w };
  bf16x4 o1 = { (bf16)y1.x, (bf16)y1.y, (bf16)y1.z, (bf16)y1.w };
  bf16x4* orow = (bf16x4*)(xn + (size_t)row * Dm);
  orow[lane]      = o0;
  orow[lane + 64] = o1;
}

// ---------------- transpose + cast: src[R][C] f32 -> dst[C][R] bf16 ----------------
__global__ __launch_bounds__(256) void tcast_kernel(
    const float* __restrict__ src, bf16* __restrict__ dst, int R, int C) {
  __shared__ float t[32][33];
  const int c0 = blockIdx.x * 32, r0 = blockIdx.y * 32;
  const int tx = threadIdx.x & 31, ty = threadIdx.x >> 5;
#pragma unroll
  for (int i = 0; i < 32; i += 8)
    t[ty + i][tx] = src[(size_t)(r0 + ty + i) * C + c0 + tx];
  __syncthreads();
#pragma unroll
  for (int i = 0; i < 32; i += 8)
    dst[(size_t)(c0 + ty + i) * R + r0 + tx] = (bf16)t[tx][ty + i];
}

// ---------------- QKV GEMM: [8192,512] x [512,1536] -> Q/K [B,H,S,64], V^T [B,H,64,S]
__global__ __launch_bounds__(256) void gemm_qkv_kernel(
    const bf16* __restrict__ A,   // [8192][512]
    const bf16* __restrict__ Bt,  // [1536][512]  (w_qkv transposed)
    bf16* __restrict__ Qb, bf16* __restrict__ Kb, bf16* __restrict__ VT) {
  constexpr int K = 512;
  __shared__ __align__(16) bf16 As[128 * 32];
  __shared__ __align__(16) bf16 Bs[128 * 32];
  const int m0 = blockIdx.x * 128, n0 = blockIdx.y * 128;
  const int tid = threadIdx.x, lane = tid & 63, wave = tid >> 6;
  const int lr = lane & 15, lg = lane >> 4;
  const int wm = (wave >> 1) * 64, wn = (wave & 1) * 64;
  const int srow = wave * 16 + (lane >> 2);
  const int scol = (lane & 3) * 8;
  const bf16* ga = A  + (size_t)(m0 + srow) * K + scol;
  const bf16* gb = Bt + (size_t)(n0 + srow) * K + scol;
  bf16* lA = As + wave * 512;
  bf16* lB = Bs + wave * 512;
  f32x4 acc[4][4] = {};
  for (int k0 = 0; k0 < K; k0 += 32) {
    g2l_16(lA,        ga + k0);
    g2l_16(lA + 2048, ga + (size_t)64 * K + k0);
    g2l_16(lB,        gb + k0);
    g2l_16(lB + 2048, gb + (size_t)64 * K + k0);
    asm volatile("s_waitcnt vmcnt(0)" ::: "memory");
    __syncthreads();
    bf16x8 af[4], bfr[4];
#pragma unroll
    for (int i = 0; i < 4; ++i)
      af[i] = *(const bf16x8*)&As[(wm + i * 16 + lr) * 32 + lg * 8];
#pragma unroll
    for (int j = 0; j < 4; ++j)
      bfr[j] = *(const bf16x8*)&Bs[(wn + j * 16 + lr) * 32 + lg * 8];
#pragma unroll
    for (int i = 0; i < 4; ++i)
#pragma unroll
      for (int j = 0; j < 4; ++j)
        acc[i][j] = MFMA16(af[i], bfr[j], acc[i][j]);
    __syncthreads();
  }
#pragma unroll
  for (int j = 0; j < 4; ++j) {
    const int n = n0 + wn + j * 16 + lr;
    const int which = n >> 9, h = (n >> 6) & 7, dh = n & 63;
    if (which < 2) {
      bf16* dst = which == 0 ? Qb : Kb;
#pragma unroll
      for (int i = 0; i < 4; ++i)
#pragma unroll
        for (int r = 0; r < 4; ++r) {
          const int m = m0 + wm + i * 16 + lg * 4 + r;
          const int b = m >> 11, s2 = m & 2047;
          dst[((size_t)((b * Hh + h) * Seq + s2) << 6) | dh] = (bf16)acc[i][j][r];
        }
    } else {
      // V: write transposed [bh][dh][s]
#pragma unroll
      for (int i = 0; i < 4; ++i)
#pragma unroll
        for (int r = 0; r < 4; ++r) {
          const int m = m0 + wm + i * 16 + lg * 4 + r;
          const int b = m >> 11, s2 = m & 2047;
          VT[((size_t)((b * Hh + h) * Dh + dh)) * Seq + s2] = (bf16)acc[i][j][r];
        }
    }
  }
}

// ---------------- Out GEMM: [8192,512] x [512,512] + bias -> fp32 out --------------
__global__ __launch_bounds__(256) void gemm_out_kernel(
    const bf16* __restrict__ A,   // [8192][512] attention output
    const bf16* __restrict__ Bt,  // [512][512]  (w_out transposed)
    const float* __restrict__ bias, float* __restrict__ out) {
  constexpr int K = 512;
  __shared__ __align__(16) bf16 As[128 * 32];
  __shared__ __align__(16) bf16 Bs[128 * 32];
  const int m0 = blockIdx.x * 128, n0 = blockIdx.y * 128;
  const int tid = threadIdx.x, lane = tid & 63, wave = tid >> 6;
  const int lr = lane & 15, lg = lane >> 4;
  const int wm = (wave >> 1) * 64, wn = (wave & 1) * 64;
  const int srow = wave * 16 + (lane >> 2);
  const int scol = (lane & 3) * 8;
  const bf16* ga = A  + (size_t)(m0 + srow) * K + scol;
  const bf16* gb = Bt + (size_t)(n0 + srow) * K + scol;
  bf16* lA = As + wave * 512;
  bf16* lB = Bs + wave * 512;
  f32x4 acc[4][4] = {};
  for (int k0 = 0; k0 < K; k0 += 32) {
    g2l_16(lA,        ga + k0);
    g2l_16(lA + 2048, ga + (size_t)64 * K + k0);
    g2l_16(lB,        gb + k0);
    g2l_16(lB + 2048, gb + (size_t)64 * K + k0);
    asm volatile("s_waitcnt vmcnt(0)" ::: "memory");
    __syncthreads();
    bf16x8 af[4], bfr[4];
#pragma unroll
    for (int i = 0; i < 4; ++i)
      af[i] = *(const bf16x8*)&As[(wm + i * 16 + lr) * 32 + lg * 8];
#pragma unroll
    for (int j = 0; j < 4; ++j)
      bfr[j] = *(const bf16x8*)&Bs[(wn + j * 16 + lr) * 32 + lg * 8];
#pragma unroll
    for (int i = 0; i < 4; ++i)
#pragma unroll
      for (int j = 0; j < 4; ++j)
        acc[i][j] = MFMA16(af[i], bfr[j], acc[i][j]);
    __syncthreads();
  }
#pragma unroll
  for (int j = 0; j < 4; ++j) {
    const int n = n0 + wn + j * 16 + lr;
    const float bv = bias[n];
#pragma unroll
    for (int i = 0; i < 4; ++i)
#pragma unroll
      for (int r = 0; r < 4; ++r) {
        const int m = m0 + wm + i * 16 + lg * 4 + r;
        out[(size_t)m * 512 + n] = acc[i][j][r] + bv;
      }
  }
}

// ---------------- Flash attention v2: swapped QK^T, barrier-free -------------------
// 4 waves x 16 queries (QBLK=64), KVBLK=64. K and V^T fragments read from global
// (L2-resident). P through wave-private LDS (stride 72 = 9x16B, conflict-free).
__global__ __launch_bounds__(256) void attn2_kernel(
    const bf16* __restrict__ Qb, const bf16* __restrict__ Kb,
    const bf16* __restrict__ VT, bf16* __restrict__ A2) {
  // bijective XCD-chunked swizzle: each XCD gets 4 complete heads (KV fits L2)
  const int o   = blockIdx.x + gridDim.x * blockIdx.y;  // 0..1023
  const int nid = ((o & 7) << 7) + (o >> 3);
  const int qc = nid & 31, bh = nid >> 5;
  const int b = bh >> 3, h = bh & 7;
  const int tid = threadIdx.x, lane = tid & 63, wave = tid >> 6;
  const int lr = lane & 15, lg = lane >> 4;
  const int q0 = qc * 64 + wave * 16;
  const bf16* Qh = Qb + (size_t)bh * Seq * Dh;
  const bf16* Kh = Kb + (size_t)bh * Seq * Dh;
  const bf16* Vh = VT + (size_t)bh * Dh * Seq;
  __shared__ __align__(16) bf16 Pl[4][16][72];
  bf16 (*P)[72] = Pl[wave];

  bf16x8 qf0 = *(const bf16x8*)&Qh[(size_t)(q0 + lr) * 64 + lg * 8];
  bf16x8 qf1 = *(const bf16x8*)&Qh[(size_t)(q0 + lr) * 64 + 32 + lg * 8];
  f32x4 oa[4] = {};
  float m = -1e30f, l = 0.0f;
  const float K1 = 0.18033688011112042f;  // 64^-0.5 * log2(e)

  for (int t0 = 0; t0 < Seq; t0 += 64) {
    // S^T = K Q^T : lane holds S[k = t0+c*16+lg*4+j][q = q0+lr]
    f32x4 st[4] = {};
#pragma unroll
    for (int c = 0; c < 4; ++c) {
      const bf16* kp = &Kh[(size_t)(t0 + c * 16 + lr) * 64 + lg * 8];
      bf16x8 kf0 = *(const bf16x8*)kp;
      bf16x8 kf1 = *(const bf16x8*)(kp + 32);
      st[c] = MFMA16(kf0, qf0, st[c]);
      st[c] = MFMA16(kf1, qf1, st[c]);
    }
    // softmax (exp2 domain), reduce over 16 in-reg + 2 shuffles
    float v_[4][4];
    float mx = -1e30f;
#pragma unroll
    for (int c = 0; c < 4; ++c)
#pragma unroll
      for (int j = 0; j < 4; ++j) {
        float z = st[c][j] * K1;
        v_[c][j] = z;
        mx = fmaxf(mx, z);
      }
    mx = fmaxf(mx, __shfl_xor(mx, 16));
    mx = fmaxf(mx, __shfl_xor(mx, 32));
    if (__any(mx > m)) {           // defer-max: rescale only when max grows
      const float mn = fmaxf(m, mx);
      const float al = exp2f(m - mn);
      m = mn;
      l *= al;
#pragma unroll
      for (int j = 0; j < 4; ++j) {
        const float aj = __shfl(al, lg * 4 + j);
#pragma unroll
        for (int n = 0; n < 4; ++n) oa[n][j] *= aj;
      }
    }
    float ps = 0.0f;
#pragma unroll
    for (int c = 0; c < 4; ++c) {
      bf16x4 pk;
#pragma unroll
      for (int j = 0; j < 4; ++j) {
        const float p = exp2f(v_[c][j] - m);
        ps += p;
        pk[j] = (bf16)p;
      }
      *(bf16x4*)&P[lr][c * 16 + lg * 4] = pk;   // P[q-row][k], packed b64
    }
    ps += __shfl_xor(ps, 16);
    ps += __shfl_xor(ps, 32);
    l += ps;
    // PV: O[q][d] += P[q][k] * V[k][d], V^T fragments from global (L2)
    bf16x8 pf0 = *(const bf16x8*)&P[lr][lg * 8];
    bf16x8 pf1 = *(const bf16x8*)&P[lr][32 + lg * 8];
#pragma unroll
    for (int n = 0; n < 4; ++n) {
      const bf16* vp = &Vh[(size_t)(n * 16 + lr) * Seq + t0 + lg * 8];
      bf16x8 vf0 = *(const bf16x8*)vp;
      bf16x8 vf1 = *(const bf16x8*)(vp + 32);
      oa[n] = MFMA16(pf0, vf0, oa[n]);
      oa[n] = MFMA16(pf1, vf1, oa[n]);
    }
  }
  // epilogue: normalize, write [B*S, 512] bf16
  const float linv = 1.0f / l;
#pragma unroll
  for (int j = 0; j < 4; ++j) {
    const float lj = __shfl(linv, lg * 4 + j);
    const int s2 = q0 + lg * 4 + j;
#pragma unroll
    for (int n = 0; n < 4; ++n)
      A2[(size_t)(b * Seq + s2) * 512 + h * 64 + n * 16 + lr] = (bf16)(oa[n][j] * lj);
  }
}

extern "C" void kernel_launch(void* const* d_in, const int* in_sizes, int n_in,
                              void* d_out, int out_size, void* d_ws, size_t ws_size,
                              hipStream_t stream) {
  const float* x    = (const float*)d_in[0];
  const float* gam  = (const float*)d_in[1];
  const float* bet  = (const float*)d_in[2];
  const float* wqkv = (const float*)d_in[3];  // [512][1536]
  const float* wout = (const float*)d_in[4];  // [512][512]
  const float* bout = (const float*)d_in[5];  // [512]
  float* out = (float*)d_out;

  bf16* xn    = (bf16*)d_ws;                        // [8192][512]   8 MB
  bf16* wqkvT = xn    + (size_t)8192 * 512;         // [1536][512]   1.5 MB
  bf16* woutT = wqkvT + (size_t)1536 * 512;         // [512][512]    0.5 MB
  bf16* Qb    = woutT + (size_t)512 * 512;          // [4,8,2048,64] 8 MB
  bf16* Kb    = Qb    + (size_t)4 * 8 * 2048 * 64;
  bf16* VT    = Kb    + (size_t)4 * 8 * 2048 * 64;  // [4,8,64,2048] 8 MB
  bf16* A2    = xn;  // reuse: xn dead after QKV GEMM

  ln_cast_kernel<<<2048, 256, 0, stream>>>(x, gam, bet, xn);
  tcast_kernel<<<dim3(48, 16), 256, 0, stream>>>(wqkv, wqkvT, 512, 1536);
  tcast_kernel<<<dim3(16, 16), 256, 0, stream>>>(wout, woutT, 512, 512);
  gemm_qkv_kernel<<<dim3(64, 12), 256, 0, stream>>>(xn, wqkvT, Qb, Kb, VT);
  attn2_kernel<<<dim3(32, 32), 256, 0, stream>>>(Qb, Kb, VT, A2);
  gemm_out_kernel<<<dim3(64, 4), 256, 0, stream>>>(A2, woutT, bout, out);
}

// Round 3
// 125.148 us; speedup vs baseline: 2.2136x; 2.2136x over previous
//
#include <hip/hip_runtime.h>
#include <hip/hip_bf16.h>
#include <stdint.h>

typedef __bf16 bf16;
typedef __bf16 bf16x8 __attribute__((ext_vector_type(8)));
typedef __bf16 bf16x4 __attribute__((ext_vector_type(4)));
typedef float  f32x4  __attribute__((ext_vector_type(4)));

#define MFMA16(A, B, C) __builtin_amdgcn_mfma_f32_16x16x32_bf16((A), (B), (C), 0, 0, 0)

static constexpr int Bsz = 4, Seq = 2048, Dm = 512, Hh = 8, Dh = 64;

__device__ __forceinline__ void g2l_16(void* lds, const void* gp) {
  __builtin_amdgcn_global_load_lds((__attribute__((address_space(1))) void*)gp,
                                   (__attribute__((address_space(3))) void*)lds, 16, 0, 0);
}

// ---------------- LayerNorm fp32 -> bf16, one wave per row (D=512) ----------------
__global__ __launch_bounds__(256) void ln_cast_kernel(
    const float* __restrict__ x, const float* __restrict__ g,
    const float* __restrict__ be, bf16* __restrict__ xn) {
  const int row  = blockIdx.x * 4 + (threadIdx.x >> 6);
  const int lane = threadIdx.x & 63;
  const f32x4* xr = (const f32x4*)(x + (size_t)row * Dm);
  f32x4 v0 = xr[lane];
  f32x4 v1 = xr[lane + 64];
  float s = (v0.x + v0.y + v0.z + v0.w) + (v1.x + v1.y + v1.z + v1.w);
#pragma unroll
  for (int off = 32; off > 0; off >>= 1) s += __shfl_xor(s, off);
  const float mu = s * (1.0f / Dm);
  f32x4 d0 = v0 - mu, d1 = v1 - mu;
  float q = d0.x * d0.x + d0.y * d0.y + d0.z * d0.z + d0.w * d0.w
          + d1.x * d1.x + d1.y * d1.y + d1.z * d1.z + d1.w * d1.w;
#pragma unroll
  for (int off = 32; off > 0; off >>= 1) q += __shfl_xor(q, off);
  const float rs = rsqrtf(q * (1.0f / Dm) + 1e-5f);
  const f32x4* gr = (const f32x4*)g;
  const f32x4* br = (const f32x4*)be;
  f32x4 g0 = gr[lane], g1 = gr[lane + 64];
  f32x4 b0 = br[lane], b1 = br[lane + 64];
  f32x4 y0 = d0 * rs * g0 + b0;
  f32x4 y1 = d1 * rs * g1 + b1;
  bf16x4 o0 = { (bf16)y0.x, (bf16)y0.y, (bf16)y0.z, (bf16)y0.w };
  bf16x4 o1 = { (bf16)y1.x, (bf16)y1.y, (bf16)y1.z, (bf16)y1.w };
  bf16x4* orow = (bf16x4*)(xn + (size_t)row * Dm);
  orow[lane]      = o0;
  orow[lane + 64] = o1;
}

// ---------------- transpose + cast: src[R][C] f32 -> dst[C][R] bf16 ----------------
__global__ __launch_bounds__(256) void tcast_kernel(
    const float* __restrict__ src, bf16* __restrict__ dst, int R, int C) {
  __shared__ float t[32][33];
  const int c0 = blockIdx.x * 32, r0 = blockIdx.y * 32;
  const int tx = threadIdx.x & 31, ty = threadIdx.x >> 5;
#pragma unroll
  for (int i = 0; i < 32; i += 8)
    t[ty + i][tx] = src[(size_t)(r0 + ty + i) * C + c0 + tx];
  __syncthreads();
#pragma unroll
  for (int i = 0; i < 32; i += 8)
    dst[(size_t)(c0 + ty + i) * R + r0 + tx] = (bf16)t[tx][ty + i];
}

// ---------------- QKV GEMM: [8192,512] x [512,1536] -> Q/K [B,H,S,64], V^T [B,H,64,S]
__global__ __launch_bounds__(256) void gemm_qkv_kernel(
    const bf16* __restrict__ A,   // [8192][512]
    const bf16* __restrict__ Bt,  // [1536][512]  (w_qkv transposed)
    bf16* __restrict__ Qb, bf16* __restrict__ Kb, bf16* __restrict__ VT) {
  constexpr int K = 512;
  __shared__ __align__(16) bf16 As[128 * 32];
  __shared__ __align__(16) bf16 Bs[128 * 32];
  const int m0 = blockIdx.x * 128, n0 = blockIdx.y * 128;
  const int tid = threadIdx.x, lane = tid & 63, wave = tid >> 6;
  const int lr = lane & 15, lg = lane >> 4;
  const int wm = (wave >> 1) * 64, wn = (wave & 1) * 64;
  const int srow = wave * 16 + (lane >> 2);
  const int scol = (lane & 3) * 8;
  const bf16* ga = A  + (size_t)(m0 + srow) * K + scol;
  const bf16* gb = Bt + (size_t)(n0 + srow) * K + scol;
  bf16* lA = As + wave * 512;
  bf16* lB = Bs + wave * 512;
  f32x4 acc[4][4] = {};
  for (int k0 = 0; k0 < K; k0 += 32) {
    g2l_16(lA,        ga + k0);
    g2l_16(lA + 2048, ga + (size_t)64 * K + k0);
    g2l_16(lB,        gb + k0);
    g2l_16(lB + 2048, gb + (size_t)64 * K + k0);
    asm volatile("s_waitcnt vmcnt(0)" ::: "memory");
    __syncthreads();
    bf16x8 af[4], bfr[4];
#pragma unroll
    for (int i = 0; i < 4; ++i)
      af[i] = *(const bf16x8*)&As[(wm + i * 16 + lr) * 32 + lg * 8];
#pragma unroll
    for (int j = 0; j < 4; ++j)
      bfr[j] = *(const bf16x8*)&Bs[(wn + j * 16 + lr) * 32 + lg * 8];
#pragma unroll
    for (int i = 0; i < 4; ++i)
#pragma unroll
      for (int j = 0; j < 4; ++j)
        acc[i][j] = MFMA16(af[i], bfr[j], acc[i][j]);
    __syncthreads();
  }
#pragma unroll
  for (int j = 0; j < 4; ++j) {
    const int n = n0 + wn + j * 16 + lr;
    const int which = n >> 9, h = (n >> 6) & 7, dh = n & 63;
    if (which < 2) {
      bf16* dst = which == 0 ? Qb : Kb;
#pragma unroll
      for (int i = 0; i < 4; ++i)
#pragma unroll
        for (int r = 0; r < 4; ++r) {
          const int m = m0 + wm + i * 16 + lg * 4 + r;
          const int b = m >> 11, s2 = m & 2047;
          dst[((size_t)((b * Hh + h) * Seq + s2) << 6) | dh] = (bf16)acc[i][j][r];
        }
    } else {
      // V: write transposed [bh][dh][s]
#pragma unroll
      for (int i = 0; i < 4; ++i)
#pragma unroll
        for (int r = 0; r < 4; ++r) {
          const int m = m0 + wm + i * 16 + lg * 4 + r;
          const int b = m >> 11, s2 = m & 2047;
          VT[((size_t)((b * Hh + h) * Dh + dh)) * Seq + s2] = (bf16)acc[i][j][r];
        }
    }
  }
}

// ---------------- Out GEMM: [8192,512] x [512,512] + bias -> fp32 out --------------
__global__ __launch_bounds__(256) void gemm_out_kernel(
    const bf16* __restrict__ A,   // [8192][512] attention output
    const bf16* __restrict__ Bt,  // [512][512]  (w_out transposed)
    const float* __restrict__ bias, float* __restrict__ out) {
  constexpr int K = 512;
  __shared__ __align__(16) bf16 As[128 * 32];
  __shared__ __align__(16) bf16 Bs[128 * 32];
  const int m0 = blockIdx.x * 128, n0 = blockIdx.y * 128;
  const int tid = threadIdx.x, lane = tid & 63, wave = tid >> 6;
  const int lr = lane & 15, lg = lane >> 4;
  const int wm = (wave >> 1) * 64, wn = (wave & 1) * 64;
  const int srow = wave * 16 + (lane >> 2);
  const int scol = (lane & 3) * 8;
  const bf16* ga = A  + (size_t)(m0 + srow) * K + scol;
  const bf16* gb = Bt + (size_t)(n0 + srow) * K + scol;
  bf16* lA = As + wave * 512;
  bf16* lB = Bs + wave * 512;
  f32x4 acc[4][4] = {};
  for (int k0 = 0; k0 < K; k0 += 32) {
    g2l_16(lA,        ga + k0);
    g2l_16(lA + 2048, ga + (size_t)64 * K + k0);
    g2l_16(lB,        gb + k0);
    g2l_16(lB + 2048, gb + (size_t)64 * K + k0);
    asm volatile("s_waitcnt vmcnt(0)" ::: "memory");
    __syncthreads();
    bf16x8 af[4], bfr[4];
#pragma unroll
    for (int i = 0; i < 4; ++i)
      af[i] = *(const bf16x8*)&As[(wm + i * 16 + lr) * 32 + lg * 8];
#pragma unroll
    for (int j = 0; j < 4; ++j)
      bfr[j] = *(const bf16x8*)&Bs[(wn + j * 16 + lr) * 32 + lg * 8];
#pragma unroll
    for (int i = 0; i < 4; ++i)
#pragma unroll
      for (int j = 0; j < 4; ++j)
        acc[i][j] = MFMA16(af[i], bfr[j], acc[i][j]);
    __syncthreads();
  }
#pragma unroll
  for (int j = 0; j < 4; ++j) {
    const int n = n0 + wn + j * 16 + lr;
    const float bv = bias[n];
#pragma unroll
    for (int i = 0; i < 4; ++i)
#pragma unroll
      for (int r = 0; r < 4; ++r) {
        const int m = m0 + wm + i * 16 + lg * 4 + r;
        out[(size_t)m * 512 + n] = acc[i][j][r] + bv;
      }
  }
}

// ---------------- Flash attention v3: LDS-staged K/V double-buffer + swizzle -------
// QBLK=128 (4 waves x 32 q), KVBLK=64. Swapped QK^T, in-register softmax,
// defer-max THR=3 (exp2 domain). K/V staged once per block via global_load_lds
// with pre-swizzled source (XOR byte^((row&7)<<4)); conflict-free ds_read_b128.
__global__ __launch_bounds__(256) void attn3_kernel(
    const bf16* __restrict__ Qb, const bf16* __restrict__ Kb,
    const bf16* __restrict__ VT, bf16* __restrict__ A2) {
  // bijective XCD-chunked swizzle: 512 blocks -> 64/XCD -> 4 complete heads/XCD
  const int o   = blockIdx.x + gridDim.x * blockIdx.y;  // 0..511
  const int nid = ((o & 7) << 6) + (o >> 3);
  const int qc = nid & 15, bh = nid >> 4;
  const int b = bh >> 3, h = bh & 7;
  const int tid = threadIdx.x, lane = tid & 63, wave = tid >> 6;
  const int lr = lane & 15, lg = lane >> 4;
  const int q0 = qc * 128 + wave * 32;
  const bf16* Qh = Qb + (size_t)bh * Seq * Dh;
  const bf16* Kh = Kb + (size_t)bh * Seq * Dh;
  const bf16* Vh = VT + (size_t)bh * Dh * Seq;

  __shared__ __align__(16) bf16 Kt[2][64 * 64];
  __shared__ __align__(16) bf16 Vt[2][64 * 64];
  __shared__ __align__(16) bf16 Pl[4][2][16][72];

  // staging geometry: round r covers LDS bytes [r*4096 + wave*1024 + lane*16, +16)
  const int soff0 = wave * 1024 + lane * 16;
  const int soff1 = soff0 + 4096;
  const int krow0 = soff0 >> 7, kc0 = ((((soff0 >> 4) & 7) ^ (krow0 & 7)) * 8);
  const int krow1 = soff1 >> 7, kc1 = ((((soff1 >> 4) & 7) ^ (krow1 & 7)) * 8);

  const bf16 *Kc = Kt[0], *Vc = Vt[0];
  bf16 *Kn = Kt[1], *Vn = Vt[1];

  auto STAGE = [&](bf16* kb, bf16* vb, int t0) {
    g2l_16(kb + wave * 512,        Kh + (size_t)(t0 + krow0) * 64 + kc0);
    g2l_16(kb + 2048 + wave * 512, Kh + (size_t)(t0 + krow1) * 64 + kc1);
    g2l_16(vb + wave * 512,        Vh + (size_t)krow0 * Seq + t0 + kc0);
    g2l_16(vb + 2048 + wave * 512, Vh + (size_t)krow1 * Seq + t0 + kc1);
  };

  bf16x8 qf[2][2];
#pragma unroll
  for (int r = 0; r < 2; ++r) {
    qf[r][0] = *(const bf16x8*)&Qh[(size_t)(q0 + r * 16 + lr) * 64 + lg * 8];
    qf[r][1] = *(const bf16x8*)&Qh[(size_t)(q0 + r * 16 + lr) * 64 + 32 + lg * 8];
  }

  f32x4 oa[2][4] = {};
  float mreg[2] = { -1e30f, -1e30f }, lreg[2] = { 0.0f, 0.0f };
  const float K1 = 0.18033688011112042f;  // 64^-0.5 * log2(e)
  const int xs = (lr & 7);                // row-dependent swizzle term

  // prologue: stage tile 0 into current buffers
  STAGE((bf16*)Kc, (bf16*)Vc, 0);
  asm volatile("s_waitcnt vmcnt(0)" ::: "memory");
  __syncthreads();

  for (int t0 = 0; t0 < Seq; t0 += 64) {
    if (t0 + 64 < Seq) STAGE(Kn, Vn, t0 + 64);  // prefetch next tile (async)

    // S^T = K Q^T : lane holds S[k = c*16+lg*4+j][q = q0+r*16+lr]
    f32x4 st[2][4] = {};
#pragma unroll
    for (int c = 0; c < 4; ++c) {
      const int krow = (c * 16 + lr) * 64;
      bf16x8 kf0 = *(const bf16x8*)&Kc[krow + ((lg ^ xs) * 8)];
      bf16x8 kf1 = *(const bf16x8*)&Kc[krow + (((4 + lg) ^ xs) * 8)];
      st[0][c] = MFMA16(kf0, qf[0][0], st[0][c]);
      st[0][c] = MFMA16(kf1, qf[0][1], st[0][c]);
      st[1][c] = MFMA16(kf0, qf[1][0], st[1][c]);
      st[1][c] = MFMA16(kf1, qf[1][1], st[1][c]);
    }

    // in-register online softmax (exp2 domain), defer-max THR=3
#pragma unroll
    for (int r = 0; r < 2; ++r) {
      float mx = -1e30f;
#pragma unroll
      for (int c = 0; c < 4; ++c)
#pragma unroll
        for (int j = 0; j < 4; ++j) {
          float z = st[r][c][j] * K1;
          st[r][c][j] = z;
          mx = fmaxf(mx, z);
        }
      mx = fmaxf(mx, __shfl_xor(mx, 16));
      mx = fmaxf(mx, __shfl_xor(mx, 32));
      if (__any(mx > mreg[r] + 3.0f)) {
        const float mn = fmaxf(mreg[r], mx);
        const float al = exp2f(mreg[r] - mn);
        mreg[r] = mn;
        lreg[r] *= al;
#pragma unroll
        for (int j = 0; j < 4; ++j) {
          const float aj = __shfl(al, lg * 4 + j);
#pragma unroll
          for (int n = 0; n < 4; ++n) oa[r][n][j] *= aj;
        }
      }
      float ps = 0.0f;
#pragma unroll
      for (int c = 0; c < 4; ++c) {
        bf16x4 pk;
#pragma unroll
        for (int j = 0; j < 4; ++j) {
          const float p = exp2f(st[r][c][j] - mreg[r]);
          ps += p;
          pk[j] = (bf16)p;
        }
        *(bf16x4*)&Pl[wave][r][lr][c * 16 + lg * 4] = pk;
      }
      ps += __shfl_xor(ps, 16);
      ps += __shfl_xor(ps, 32);
      lreg[r] += ps;
    }

    // PV: O[q][d] += P[q][k] * V[k][d]
    bf16x8 pf[2][2];
#pragma unroll
    for (int r = 0; r < 2; ++r) {
      pf[r][0] = *(const bf16x8*)&Pl[wave][r][lr][lg * 8];
      pf[r][1] = *(const bf16x8*)&Pl[wave][r][lr][32 + lg * 8];
    }
#pragma unroll
    for (int n = 0; n < 4; ++n) {
      const int vrow = (n * 16 + lr) * 64;
      bf16x8 vf0 = *(const bf16x8*)&Vc[vrow + ((lg ^ xs) * 8)];
      bf16x8 vf1 = *(const bf16x8*)&Vc[vrow + (((4 + lg) ^ xs) * 8)];
      oa[0][n] = MFMA16(pf[0][0], vf0, oa[0][n]);
      oa[0][n] = MFMA16(pf[0][1], vf1, oa[0][n]);
      oa[1][n] = MFMA16(pf[1][0], vf0, oa[1][n]);
      oa[1][n] = MFMA16(pf[1][1], vf1, oa[1][n]);
    }

    // staged loads landed; all waves done reading current buffers
    asm volatile("s_waitcnt vmcnt(0)" ::: "memory");
    __syncthreads();
    bf16* tk = (bf16*)Kc; Kc = Kn; Kn = tk;
    bf16* tv = (bf16*)Vc; Vc = Vn; Vn = tv;
  }

  // epilogue: normalize, write [B*S, 512] bf16
#pragma unroll
  for (int r = 0; r < 2; ++r) {
    const float linv = 1.0f / lreg[r];
#pragma unroll
    for (int j = 0; j < 4; ++j) {
      const float lj = __shfl(linv, lg * 4 + j);
      const int s2 = q0 + r * 16 + lg * 4 + j;
#pragma unroll
      for (int n = 0; n < 4; ++n)
        A2[(size_t)(b * Seq + s2) * 512 + h * 64 + n * 16 + lr] = (bf16)(oa[r][n][j] * lj);
    }
  }
}

extern "C" void kernel_launch(void* const* d_in, const int* in_sizes, int n_in,
                              void* d_out, int out_size, void* d_ws, size_t ws_size,
                              hipStream_t stream) {
  const float* x    = (const float*)d_in[0];
  const float* gam  = (const float*)d_in[1];
  const float* bet  = (const float*)d_in[2];
  const float* wqkv = (const float*)d_in[3];  // [512][1536]
  const float* wout = (const float*)d_in[4];  // [512][512]
  const float* bout = (const float*)d_in[5];  // [512]
  float* out = (float*)d_out;

  bf16* xn    = (bf16*)d_ws;                        // [8192][512]   8 MB
  bf16* wqkvT = xn    + (size_t)8192 * 512;         // [1536][512]   1.5 MB
  bf16* woutT = wqkvT + (size_t)1536 * 512;         // [512][512]    0.5 MB
  bf16* Qb    = woutT + (size_t)512 * 512;          // [4,8,2048,64] 8 MB
  bf16* Kb    = Qb    + (size_t)4 * 8 * 2048 * 64;
  bf16* VT    = Kb    + (size_t)4 * 8 * 2048 * 64;  // [4,8,64,2048] 8 MB
  bf16* A2    = xn;  // reuse: xn dead after QKV GEMM

  ln_cast_kernel<<<2048, 256, 0, stream>>>(x, gam, bet, xn);
  tcast_kernel<<<dim3(48, 16), 256, 0, stream>>>(wqkv, wqkvT, 512, 1536);
  tcast_kernel<<<dim3(16, 16), 256, 0, stream>>>(wout, woutT, 512, 512);
  gemm_qkv_kernel<<<dim3(64, 12), 256, 0, stream>>>(xn, wqkvT, Qb, Kb, VT);
  attn3_kernel<<<dim3(16, 32), 256, 0, stream>>>(Qb, Kb, VT, A2);
  gemm_out_kernel<<<dim3(64, 4), 256, 0, stream>>>(A2, woutT, bout, out);
}

// Round 4
// 109.957 us; speedup vs baseline: 2.5194x; 1.1381x over previous
//
#include <hip/hip_runtime.h>
#include <hip/hip_bf16.h>
#include <stdint.h>

typedef __bf16 bf16;
typedef __bf16 bf16x8 __attribute__((ext_vector_type(8)));
typedef __bf16 bf16x4 __attribute__((ext_vector_type(4)));
typedef float  f32x4  __attribute__((ext_vector_type(4)));

#define MFMA16(A, B, C) __builtin_amdgcn_mfma_f32_16x16x32_bf16((A), (B), (C), 0, 0, 0)

static constexpr int Bsz = 4, Seq = 2048, Dm = 512, Hh = 8, Dh = 64;

__device__ __forceinline__ void g2l_16(void* lds, const void* gp) {
  __builtin_amdgcn_global_load_lds((__attribute__((address_space(1))) void*)gp,
                                   (__attribute__((address_space(3))) void*)lds, 16, 0, 0);
}

__device__ __forceinline__ float max3f(float a, float b, float c) {
  return fmaxf(fmaxf(a, b), c);   // clang fuses to v_max3_f32
}

// ---------------- LayerNorm fp32 -> bf16, one wave per row (D=512) ----------------
__global__ __launch_bounds__(256) void ln_cast_kernel(
    const float* __restrict__ x, const float* __restrict__ g,
    const float* __restrict__ be, bf16* __restrict__ xn) {
  const int row  = blockIdx.x * 4 + (threadIdx.x >> 6);
  const int lane = threadIdx.x & 63;
  const f32x4* xr = (const f32x4*)(x + (size_t)row * Dm);
  f32x4 v0 = xr[lane];
  f32x4 v1 = xr[lane + 64];
  float s = (v0.x + v0.y + v0.z + v0.w) + (v1.x + v1.y + v1.z + v1.w);
#pragma unroll
  for (int off = 32; off > 0; off >>= 1) s += __shfl_xor(s, off);
  const float mu = s * (1.0f / Dm);
  f32x4 d0 = v0 - mu, d1 = v1 - mu;
  float q = d0.x * d0.x + d0.y * d0.y + d0.z * d0.z + d0.w * d0.w
          + d1.x * d1.x + d1.y * d1.y + d1.z * d1.z + d1.w * d1.w;
#pragma unroll
  for (int off = 32; off > 0; off >>= 1) q += __shfl_xor(q, off);
  const float rs = rsqrtf(q * (1.0f / Dm) + 1e-5f);
  const f32x4* gr = (const f32x4*)g;
  const f32x4* br = (const f32x4*)be;
  f32x4 g0 = gr[lane], g1 = gr[lane + 64];
  f32x4 b0 = br[lane], b1 = br[lane + 64];
  f32x4 y0 = d0 * rs * g0 + b0;
  f32x4 y1 = d1 * rs * g1 + b1;
  bf16x4 o0 = { (bf16)y0.x, (bf16)y0.y, (bf16)y0.z, (bf16)y0.w };
  bf16x4 o1 = { (bf16)y1.x, (bf16)y1.y, (bf16)y1.z, (bf16)y1.w };
  bf16x4* orow = (bf16x4*)(xn + (size_t)row * Dm);
  orow[lane]      = o0;
  orow[lane + 64] = o1;
}

// ------- transpose + cast: src[R][C] f32 -> dst[C][R] bf16; rows < qrows get *qscale
__global__ __launch_bounds__(256) void tcast_kernel(
    const float* __restrict__ src, bf16* __restrict__ dst, int R, int C,
    int qrows, float qscale) {
  __shared__ float t[32][33];
  const int c0 = blockIdx.x * 32, r0 = blockIdx.y * 32;
  const int tx = threadIdx.x & 31, ty = threadIdx.x >> 5;
#pragma unroll
  for (int i = 0; i < 32; i += 8)
    t[ty + i][tx] = src[(size_t)(r0 + ty + i) * C + c0 + tx];
  __syncthreads();
#pragma unroll
  for (int i = 0; i < 32; i += 8) {
    const int rr = c0 + ty + i;
    const float sc = rr < qrows ? qscale : 1.0f;
    dst[(size_t)rr * R + r0 + tx] = (bf16)(t[tx][ty + i] * sc);
  }
}

// ---------------- QKV GEMM: [8192,512] x [512,1536] -> Q/K [B,H,S,64], V^T [B,H,64,S]
__global__ __launch_bounds__(256) void gemm_qkv_kernel(
    const bf16* __restrict__ A,   // [8192][512]
    const bf16* __restrict__ Bt,  // [1536][512]  (w_qkv transposed)
    bf16* __restrict__ Qb, bf16* __restrict__ Kb, bf16* __restrict__ VT) {
  constexpr int K = 512;
  __shared__ __align__(16) bf16 As[128 * 32];
  __shared__ __align__(16) bf16 Bs[128 * 32];
  const int m0 = blockIdx.x * 128, n0 = blockIdx.y * 128;
  const int tid = threadIdx.x, lane = tid & 63, wave = tid >> 6;
  const int lr = lane & 15, lg = lane >> 4;
  const int wm = (wave >> 1) * 64, wn = (wave & 1) * 64;
  const int srow = wave * 16 + (lane >> 2);
  const int scol = (lane & 3) * 8;
  const bf16* ga = A  + (size_t)(m0 + srow) * K + scol;
  const bf16* gb = Bt + (size_t)(n0 + srow) * K + scol;
  bf16* lA = As + wave * 512;
  bf16* lB = Bs + wave * 512;
  f32x4 acc[4][4] = {};
  for (int k0 = 0; k0 < K; k0 += 32) {
    g2l_16(lA,        ga + k0);
    g2l_16(lA + 2048, ga + (size_t)64 * K + k0);
    g2l_16(lB,        gb + k0);
    g2l_16(lB + 2048, gb + (size_t)64 * K + k0);
    asm volatile("s_waitcnt vmcnt(0)" ::: "memory");
    __syncthreads();
    bf16x8 af[4], bfr[4];
#pragma unroll
    for (int i = 0; i < 4; ++i)
      af[i] = *(const bf16x8*)&As[(wm + i * 16 + lr) * 32 + lg * 8];
#pragma unroll
    for (int j = 0; j < 4; ++j)
      bfr[j] = *(const bf16x8*)&Bs[(wn + j * 16 + lr) * 32 + lg * 8];
#pragma unroll
    for (int i = 0; i < 4; ++i)
#pragma unroll
      for (int j = 0; j < 4; ++j)
        acc[i][j] = MFMA16(af[i], bfr[j], acc[i][j]);
    __syncthreads();
  }
#pragma unroll
  for (int j = 0; j < 4; ++j) {
    const int n = n0 + wn + j * 16 + lr;
    const int which = n >> 9, h = (n >> 6) & 7, dh = n & 63;
    if (which < 2) {
      bf16* dst = which == 0 ? Qb : Kb;
#pragma unroll
      for (int i = 0; i < 4; ++i)
#pragma unroll
        for (int r = 0; r < 4; ++r) {
          const int m = m0 + wm + i * 16 + lg * 4 + r;
          const int b = m >> 11, s2 = m & 2047;
          dst[((size_t)((b * Hh + h) * Seq + s2) << 6) | dh] = (bf16)acc[i][j][r];
        }
    } else {
      // V: write transposed [bh][dh][s]
#pragma unroll
      for (int i = 0; i < 4; ++i)
#pragma unroll
        for (int r = 0; r < 4; ++r) {
          const int m = m0 + wm + i * 16 + lg * 4 + r;
          const int b = m >> 11, s2 = m & 2047;
          VT[((size_t)((b * Hh + h) * Dh + dh)) * Seq + s2] = (bf16)acc[i][j][r];
        }
    }
  }
}

// ---------------- Out GEMM: [8192,512] x [512,512] + bias -> fp32 out --------------
__global__ __launch_bounds__(256) void gemm_out_kernel(
    const bf16* __restrict__ A,   // [8192][512] attention output
    const bf16* __restrict__ Bt,  // [512][512]  (w_out transposed)
    const float* __restrict__ bias, float* __restrict__ out) {
  constexpr int K = 512;
  __shared__ __align__(16) bf16 As[128 * 32];
  __shared__ __align__(16) bf16 Bs[128 * 32];
  const int m0 = blockIdx.x * 128, n0 = blockIdx.y * 128;
  const int tid = threadIdx.x, lane = tid & 63, wave = tid >> 6;
  const int lr = lane & 15, lg = lane >> 4;
  const int wm = (wave >> 1) * 64, wn = (wave & 1) * 64;
  const int srow = wave * 16 + (lane >> 2);
  const int scol = (lane & 3) * 8;
  const bf16* ga = A  + (size_t)(m0 + srow) * K + scol;
  const bf16* gb = Bt + (size_t)(n0 + srow) * K + scol;
  bf16* lA = As + wave * 512;
  bf16* lB = Bs + wave * 512;
  f32x4 acc[4][4] = {};
  for (int k0 = 0; k0 < K; k0 += 32) {
    g2l_16(lA,        ga + k0);
    g2l_16(lA + 2048, ga + (size_t)64 * K + k0);
    g2l_16(lB,        gb + k0);
    g2l_16(lB + 2048, gb + (size_t)64 * K + k0);
    asm volatile("s_waitcnt vmcnt(0)" ::: "memory");
    __syncthreads();
    bf16x8 af[4], bfr[4];
#pragma unroll
    for (int i = 0; i < 4; ++i)
      af[i] = *(const bf16x8*)&As[(wm + i * 16 + lr) * 32 + lg * 8];
#pragma unroll
    for (int j = 0; j < 4; ++j)
      bfr[j] = *(const bf16x8*)&Bs[(wn + j * 16 + lr) * 32 + lg * 8];
#pragma unroll
    for (int i = 0; i < 4; ++i)
#pragma unroll
      for (int j = 0; j < 4; ++j)
        acc[i][j] = MFMA16(af[i], bfr[j], acc[i][j]);
    __syncthreads();
  }
#pragma unroll
  for (int j = 0; j < 4; ++j) {
    const int n = n0 + wn + j * 16 + lr;
    const float bv = bias[j == 0 ? n : n];  // keep simple
#pragma unroll
    for (int i = 0; i < 4; ++i)
#pragma unroll
      for (int r = 0; r < 4; ++r) {
        const int m = m0 + wm + i * 16 + lg * 4 + r;
        out[(size_t)m * 512 + n] = acc[i][j][r] + bv;
      }
  }
}

// ---------------- Flash attention v4: 8 waves x 16q, dbuf LDS K/V, ones-MFMA l ----
// QBLK=128 (8 waves x 16 q), KVBLK=64. Scale folded into Q at weight-cast time.
// l accumulated via ones-B MFMA; epilogue shuffle-free.
__global__ __launch_bounds__(512) void attn4_kernel(
    const bf16* __restrict__ Qb, const bf16* __restrict__ Kb,
    const bf16* __restrict__ VT, bf16* __restrict__ A2) {
  // bijective XCD-chunked swizzle: 512 blocks -> 64/XCD -> 4 complete heads/XCD
  const int o   = blockIdx.x + gridDim.x * blockIdx.y;  // 0..511
  const int nid = ((o & 7) << 6) + (o >> 3);
  const int qc = nid & 15, bh = nid >> 4;
  const int b = bh >> 3, h = bh & 7;
  const int tid = threadIdx.x, lane = tid & 63, wave = tid >> 6;
  const int lr = lane & 15, lg = lane >> 4;
  const int q0 = qc * 128 + wave * 16;
  const bf16* Qh = Qb + (size_t)bh * Seq * Dh;
  const bf16* Kh = Kb + (size_t)bh * Seq * Dh;
  const bf16* Vh = VT + (size_t)bh * Dh * Seq;

  __shared__ __align__(16) bf16 Kt[2][64 * 64];
  __shared__ __align__(16) bf16 Vt[2][64 * 64];
  __shared__ __align__(16) bf16 Pl[8][16][72];

  // staging: thread covers LDS bytes [tid*16, +16); one 8KB tile per round
  const int krow = tid >> 3;
  const int kc   = (((tid & 7) ^ (krow & 7)) * 8);
  const bf16* gK = Kh + (size_t)krow * 64 + kc;    // + t0*64
  const bf16* gV = Vh + (size_t)krow * Seq + kc;   // + t0

  const bf16 *Kc = Kt[0], *Vc = Vt[0];
  bf16 *Kn = Kt[1], *Vn = Vt[1];

  bf16x8 qf0 = *(const bf16x8*)&Qh[(size_t)(q0 + lr) * 64 + lg * 8];
  bf16x8 qf1 = *(const bf16x8*)&Qh[(size_t)(q0 + lr) * 64 + 32 + lg * 8];

  f32x4 oa[4] = {};
  f32x4 ol = {};                     // ol[j] = running row-sum l for q = q0+4lg+j
  float m = -1e30f;
  const int xs = lr & 7;
  bf16x8 ones;
#pragma unroll
  for (int i = 0; i < 8; ++i) ones[i] = (bf16)1.0f;

  // prologue: stage tile 0
  g2l_16((bf16*)Kc + (size_t)tid * 8, gK);
  g2l_16((bf16*)Vc + (size_t)tid * 8, gV);
  asm volatile("s_waitcnt vmcnt(0)" ::: "memory");
  __syncthreads();

  for (int t0 = 0; t0 < Seq; t0 += 64) {
    if (t0 + 64 < Seq) {  // prefetch next tile (async)
      g2l_16(Kn + (size_t)tid * 8, gK + (size_t)(t0 + 64) * 64);
      g2l_16(Vn + (size_t)tid * 8, gV + (t0 + 64));
    }

    // S^T = K Q'^T : lane holds Z[k = c*16+lg*4+j][q = q0+lr] (already exp2-scaled)
    f32x4 st[4] = {};
#pragma unroll
    for (int c = 0; c < 4; ++c) {
      const int krw = (c * 16 + lr) * 64;
      bf16x8 kf0 = *(const bf16x8*)&Kc[krw + ((lg ^ xs) * 8)];
      bf16x8 kf1 = *(const bf16x8*)&Kc[krw + (((4 + lg) ^ xs) * 8)];
      st[c] = MFMA16(kf0, qf0, st[c]);
      st[c] = MFMA16(kf1, qf1, st[c]);
    }

    // online softmax: max via max3 tree + 2 shuffles; defer-max THR=3
    float m0 = max3f(st[0][0], st[0][1], st[0][2]);
    float m1 = max3f(st[0][3], st[1][0], st[1][1]);
    float m2 = max3f(st[1][2], st[1][3], st[2][0]);
    float m3 = max3f(st[2][1], st[2][2], st[2][3]);
    float m4 = max3f(st[3][0], st[3][1], st[3][2]);
    float mx = max3f(max3f(m0, m1, m2), max3f(m3, m4, st[3][3]), -1e30f);
    mx = fmaxf(mx, __shfl_xor(mx, 16));
    mx = fmaxf(mx, __shfl_xor(mx, 32));
    if (__any(mx > m + 3.0f)) {
      const float mn = fmaxf(m, mx);
      const float al = exp2f(m - mn);
      m = mn;
#pragma unroll
      for (int j = 0; j < 4; ++j) {
        const float aj = __shfl(al, lg * 4 + j);
        ol[j] *= aj;
#pragma unroll
        for (int n = 0; n < 4; ++n) oa[n][j] *= aj;
      }
    }
#pragma unroll
    for (int c = 0; c < 4; ++c) {
      bf16x4 pk;
#pragma unroll
      for (int j = 0; j < 4; ++j) pk[j] = (bf16)exp2f(st[c][j] - m);
      *(bf16x4*)&Pl[wave][lr][c * 16 + lg * 4] = pk;
    }

    // PV + ones-MFMA row-sum
    bf16x8 pf0 = *(const bf16x8*)&Pl[wave][lr][lg * 8];
    bf16x8 pf1 = *(const bf16x8*)&Pl[wave][lr][32 + lg * 8];
    ol = MFMA16(pf0, ones, ol);
    ol = MFMA16(pf1, ones, ol);
#pragma unroll
    for (int n = 0; n < 4; ++n) {
      const int vrw = (n * 16 + lr) * 64;
      bf16x8 vf0 = *(const bf16x8*)&Vc[vrw + ((lg ^ xs) * 8)];
      bf16x8 vf1 = *(const bf16x8*)&Vc[vrw + (((4 + lg) ^ xs) * 8)];
      oa[n] = MFMA16(pf0, vf0, oa[n]);
      oa[n] = MFMA16(pf1, vf1, oa[n]);
    }

    // staged loads landed; all waves done reading current buffers
    asm volatile("s_waitcnt vmcnt(0)" ::: "memory");
    __syncthreads();
    bf16* tk = (bf16*)Kc; Kc = Kn; Kn = tk;
    bf16* tv = (bf16*)Vc; Vc = Vn; Vn = tv;
  }

  // epilogue: normalize (l held in-lane), write [B*S, 512] bf16
#pragma unroll
  for (int j = 0; j < 4; ++j) {
    const float lj = 1.0f / ol[j];
    const int s2 = q0 + lg * 4 + j;
#pragma unroll
    for (int n = 0; n < 4; ++n)
      A2[(size_t)(b * Seq + s2) * 512 + h * 64 + n * 16 + lr] = (bf16)(oa[n][j] * lj);
  }
}

extern "C" void kernel_launch(void* const* d_in, const int* in_sizes, int n_in,
                              void* d_out, int out_size, void* d_ws, size_t ws_size,
                              hipStream_t stream) {
  const float* x    = (const float*)d_in[0];
  const float* gam  = (const float*)d_in[1];
  const float* bet  = (const float*)d_in[2];
  const float* wqkv = (const float*)d_in[3];  // [512][1536]
  const float* wout = (const float*)d_in[4];  // [512][512]
  const float* bout = (const float*)d_in[5];  // [512]
  float* out = (float*)d_out;

  bf16* xn    = (bf16*)d_ws;                        // [8192][512]   8 MB
  bf16* wqkvT = xn    + (size_t)8192 * 512;         // [1536][512]   1.5 MB
  bf16* woutT = wqkvT + (size_t)1536 * 512;         // [512][512]    0.5 MB
  bf16* Qb    = woutT + (size_t)512 * 512;          // [4,8,2048,64] 8 MB
  bf16* Kb    = Qb    + (size_t)4 * 8 * 2048 * 64;
  bf16* VT    = Kb    + (size_t)4 * 8 * 2048 * 64;  // [4,8,64,2048] 8 MB
  bf16* A2    = xn;  // reuse: xn dead after QKV GEMM

  // 64^-0.5 * log2(e) folded into Q columns of w_qkv
  const float K1 = 0.18033688011112042f;

  ln_cast_kernel<<<2048, 256, 0, stream>>>(x, gam, bet, xn);
  tcast_kernel<<<dim3(48, 16), 256, 0, stream>>>(wqkv, wqkvT, 512, 1536, 512, K1);
  tcast_kernel<<<dim3(16, 16), 256, 0, stream>>>(wout, woutT, 512, 512, 0, 1.0f);
  gemm_qkv_kernel<<<dim3(64, 12), 256, 0, stream>>>(xn, wqkvT, Qb, Kb, VT);
  attn4_kernel<<<dim3(16, 32), 512, 0, stream>>>(Qb, Kb, VT, A2);
  gemm_out_kernel<<<dim3(64, 4), 256, 0, stream>>>(A2, woutT, bout, out);
}

// Round 5
// 109.218 us; speedup vs baseline: 2.5364x; 1.0068x over previous
//
#include <hip/hip_runtime.h>
#include <hip/hip_bf16.h>
#include <stdint.h>

typedef __bf16 bf16;
typedef __bf16 bf16x8 __attribute__((ext_vector_type(8)));
typedef __bf16 bf16x4 __attribute__((ext_vector_type(4)));
typedef float  f32x4  __attribute__((ext_vector_type(4)));

#define MFMA16(A, B, C) __builtin_amdgcn_mfma_f32_16x16x32_bf16((A), (B), (C), 0, 0, 0)

static constexpr int Bsz = 4, Seq = 2048, Dm = 512, Hh = 8, Dh = 64;

__device__ __forceinline__ void g2l_16(void* lds, const void* gp) {
  __builtin_amdgcn_global_load_lds((__attribute__((address_space(1))) void*)gp,
                                   (__attribute__((address_space(3))) void*)lds, 16, 0, 0);
}

__device__ __forceinline__ float max3f(float a, float b, float c) {
  return fmaxf(fmaxf(a, b), c);   // clang fuses to v_max3_f32
}

// ---------------- LayerNorm fp32 -> bf16, one wave per row (D=512) ----------------
__global__ __launch_bounds__(256) void ln_cast_kernel(
    const float* __restrict__ x, const float* __restrict__ g,
    const float* __restrict__ be, bf16* __restrict__ xn) {
  const int row  = blockIdx.x * 4 + (threadIdx.x >> 6);
  const int lane = threadIdx.x & 63;
  const f32x4* xr = (const f32x4*)(x + (size_t)row * Dm);
  f32x4 v0 = xr[lane];
  f32x4 v1 = xr[lane + 64];
  float s = (v0.x + v0.y + v0.z + v0.w) + (v1.x + v1.y + v1.z + v1.w);
#pragma unroll
  for (int off = 32; off > 0; off >>= 1) s += __shfl_xor(s, off);
  const float mu = s * (1.0f / Dm);
  f32x4 d0 = v0 - mu, d1 = v1 - mu;
  float q = d0.x * d0.x + d0.y * d0.y + d0.z * d0.z + d0.w * d0.w
          + d1.x * d1.x + d1.y * d1.y + d1.z * d1.z + d1.w * d1.w;
#pragma unroll
  for (int off = 32; off > 0; off >>= 1) q += __shfl_xor(q, off);
  const float rs = rsqrtf(q * (1.0f / Dm) + 1e-5f);
  const f32x4* gr = (const f32x4*)g;
  const f32x4* br = (const f32x4*)be;
  f32x4 g0 = gr[lane], g1 = gr[lane + 64];
  f32x4 b0 = br[lane], b1 = br[lane + 64];
  f32x4 y0 = d0 * rs * g0 + b0;
  f32x4 y1 = d1 * rs * g1 + b1;
  bf16x4 o0 = { (bf16)y0.x, (bf16)y0.y, (bf16)y0.z, (bf16)y0.w };
  bf16x4 o1 = { (bf16)y1.x, (bf16)y1.y, (bf16)y1.z, (bf16)y1.w };
  bf16x4* orow = (bf16x4*)(xn + (size_t)row * Dm);
  orow[lane]      = o0;
  orow[lane + 64] = o1;
}

// ------- transpose + cast: src[R][C] f32 -> dst[C][R] bf16; rows < qrows get *qscale
__global__ __launch_bounds__(256) void tcast_kernel(
    const float* __restrict__ src, bf16* __restrict__ dst, int R, int C,
    int qrows, float qscale) {
  __shared__ float t[32][33];
  const int c0 = blockIdx.x * 32, r0 = blockIdx.y * 32;
  const int tx = threadIdx.x & 31, ty = threadIdx.x >> 5;
#pragma unroll
  for (int i = 0; i < 32; i += 8)
    t[ty + i][tx] = src[(size_t)(r0 + ty + i) * C + c0 + tx];
  __syncthreads();
#pragma unroll
  for (int i = 0; i < 32; i += 8) {
    const int rr = c0 + ty + i;
    const float sc = rr < qrows ? qscale : 1.0f;
    dst[(size_t)rr * R + r0 + tx] = (bf16)(t[tx][ty + i] * sc);
  }
}

// ---------------- QKV GEMM: [8192,512] x [512,1536] -> Q/K [B,H,S,64], V^T [B,H,64,S]
__global__ __launch_bounds__(256) void gemm_qkv_kernel(
    const bf16* __restrict__ A,   // [8192][512]
    const bf16* __restrict__ Bt,  // [1536][512]  (w_qkv transposed)
    bf16* __restrict__ Qb, bf16* __restrict__ Kb, bf16* __restrict__ VT) {
  constexpr int K = 512;
  __shared__ __align__(16) bf16 As[128 * 32];
  __shared__ __align__(16) bf16 Bs[128 * 32];
  const int m0 = blockIdx.x * 128, n0 = blockIdx.y * 128;
  const int tid = threadIdx.x, lane = tid & 63, wave = tid >> 6;
  const int lr = lane & 15, lg = lane >> 4;
  const int wm = (wave >> 1) * 64, wn = (wave & 1) * 64;
  const int srow = wave * 16 + (lane >> 2);
  const int scol = (lane & 3) * 8;
  const bf16* ga = A  + (size_t)(m0 + srow) * K + scol;
  const bf16* gb = Bt + (size_t)(n0 + srow) * K + scol;
  bf16* lA = As + wave * 512;
  bf16* lB = Bs + wave * 512;
  f32x4 acc[4][4] = {};
  for (int k0 = 0; k0 < K; k0 += 32) {
    g2l_16(lA,        ga + k0);
    g2l_16(lA + 2048, ga + (size_t)64 * K + k0);
    g2l_16(lB,        gb + k0);
    g2l_16(lB + 2048, gb + (size_t)64 * K + k0);
    asm volatile("s_waitcnt vmcnt(0)" ::: "memory");
    __syncthreads();
    bf16x8 af[4], bfr[4];
#pragma unroll
    for (int i = 0; i < 4; ++i)
      af[i] = *(const bf16x8*)&As[(wm + i * 16 + lr) * 32 + lg * 8];
#pragma unroll
    for (int j = 0; j < 4; ++j)
      bfr[j] = *(const bf16x8*)&Bs[(wn + j * 16 + lr) * 32 + lg * 8];
#pragma unroll
    for (int i = 0; i < 4; ++i)
#pragma unroll
      for (int j = 0; j < 4; ++j)
        acc[i][j] = MFMA16(af[i], bfr[j], acc[i][j]);
    __syncthreads();
  }
#pragma unroll
  for (int j = 0; j < 4; ++j) {
    const int n = n0 + wn + j * 16 + lr;
    const int which = n >> 9, h = (n >> 6) & 7, dh = n & 63;
    if (which < 2) {
      bf16* dst = which == 0 ? Qb : Kb;
#pragma unroll
      for (int i = 0; i < 4; ++i)
#pragma unroll
        for (int r = 0; r < 4; ++r) {
          const int m = m0 + wm + i * 16 + lg * 4 + r;
          const int b = m >> 11, s2 = m & 2047;
          dst[((size_t)((b * Hh + h) * Seq + s2) << 6) | dh] = (bf16)acc[i][j][r];
        }
    } else {
      // V: write transposed [bh][dh][s]
#pragma unroll
      for (int i = 0; i < 4; ++i)
#pragma unroll
        for (int r = 0; r < 4; ++r) {
          const int m = m0 + wm + i * 16 + lg * 4 + r;
          const int b = m >> 11, s2 = m & 2047;
          VT[((size_t)((b * Hh + h) * Dh + dh)) * Seq + s2] = (bf16)acc[i][j][r];
        }
    }
  }
}

// ---------------- Out GEMM: [8192,512] x [512,512] + bias -> fp32 out --------------
__global__ __launch_bounds__(256) void gemm_out_kernel(
    const bf16* __restrict__ A,   // [8192][512] attention output
    const bf16* __restrict__ Bt,  // [512][512]  (w_out transposed)
    const float* __restrict__ bias, float* __restrict__ out) {
  constexpr int K = 512;
  __shared__ __align__(16) bf16 As[128 * 32];
  __shared__ __align__(16) bf16 Bs[128 * 32];
  const int m0 = blockIdx.x * 128, n0 = blockIdx.y * 128;
  const int tid = threadIdx.x, lane = tid & 63, wave = tid >> 6;
  const int lr = lane & 15, lg = lane >> 4;
  const int wm = (wave >> 1) * 64, wn = (wave & 1) * 64;
  const int srow = wave * 16 + (lane >> 2);
  const int scol = (lane & 3) * 8;
  const bf16* ga = A  + (size_t)(m0 + srow) * K + scol;
  const bf16* gb = Bt + (size_t)(n0 + srow) * K + scol;
  bf16* lA = As + wave * 512;
  bf16* lB = Bs + wave * 512;
  f32x4 acc[4][4] = {};
  for (int k0 = 0; k0 < K; k0 += 32) {
    g2l_16(lA,        ga + k0);
    g2l_16(lA + 2048, ga + (size_t)64 * K + k0);
    g2l_16(lB,        gb + k0);
    g2l_16(lB + 2048, gb + (size_t)64 * K + k0);
    asm volatile("s_waitcnt vmcnt(0)" ::: "memory");
    __syncthreads();
    bf16x8 af[4], bfr[4];
#pragma unroll
    for (int i = 0; i < 4; ++i)
      af[i] = *(const bf16x8*)&As[(wm + i * 16 + lr) * 32 + lg * 8];
#pragma unroll
    for (int j = 0; j < 4; ++j)
      bfr[j] = *(const bf16x8*)&Bs[(wn + j * 16 + lr) * 32 + lg * 8];
#pragma unroll
    for (int i = 0; i < 4; ++i)
#pragma unroll
      for (int j = 0; j < 4; ++j)
        acc[i][j] = MFMA16(af[i], bfr[j], acc[i][j]);
    __syncthreads();
  }
#pragma unroll
  for (int j = 0; j < 4; ++j) {
    const int n = n0 + wn + j * 16 + lr;
    const float bv = bias[n];
#pragma unroll
    for (int i = 0; i < 4; ++i)
#pragma unroll
      for (int r = 0; r < 4; ++r) {
        const int m = m0 + wm + i * 16 + lg * 4 + r;
        out[(size_t)m * 512 + n] = acc[i][j][r] + bv;
      }
  }
}

// ------- Flash attention v5: compile-time dbuf, hoisted LDS bases, unroll x2 -------
// 8 waves x 16 q (QBLK=128), KVBLK=64. All ds_read/ds_write addresses are one of
// four per-lane base registers + immediate offset. Staging via 2 walking pointers.
__global__ __launch_bounds__(512) void attn5_kernel(
    const bf16* __restrict__ Qb, const bf16* __restrict__ Kb,
    const bf16* __restrict__ VT, bf16* __restrict__ A2) {
  // bijective XCD-chunked swizzle: 512 blocks -> 64/XCD -> 4 complete heads/XCD
  const int o   = blockIdx.x + gridDim.x * blockIdx.y;  // 0..511
  const int nid = ((o & 7) << 6) + (o >> 3);
  const int qc = nid & 15, bh = nid >> 4;
  const int b = bh >> 3, h = bh & 7;
  const int tid = threadIdx.x, lane = tid & 63, wave = tid >> 6;
  const int lr = lane & 15, lg = lane >> 4;
  const int q0 = qc * 128 + wave * 16;
  const bf16* Qh = Qb + (size_t)bh * Seq * Dh;
  const bf16* Kh = Kb + (size_t)bh * Seq * Dh;
  const bf16* Vh = VT + (size_t)bh * Dh * Seq;

  // KV[buf] : elements [0,4096) = K tile (swizzled), [4096,8192) = V tile (swizzled)
  __shared__ __align__(16) bf16 KV[2][8192];
  __shared__ __align__(16) bf16 Pl[8][16][72];

  // hoisted per-lane LDS bases (elements)
  const int xs   = lr & 7;
  const int col0 = (lg ^ xs) * 8;
  const bf16* kv  = &KV[0][0];
  const int kb0 = lr * 64 + col0;          // frag0 base; + buf*8192 + c*1024 (K) / +4096+n*1024 (V)
  const int kb1 = lr * 64 + (col0 ^ 32);   // frag1 base
  bf16* pw = &Pl[wave][lr][lg * 4];        // writes: pw[c*32 - lg*4 + lg*4] -> pw2 form below
  const bf16* pr = &Pl[wave][lr][lg * 8];  // reads: pr[0], pr[32]

  // staging: thread covers LDS bytes [tid*16, +16) of each 8KB half-tile
  const int krow = tid >> 3;
  const int kc   = (((tid & 7) ^ (krow & 7)) * 8);
  const bf16* gK = Kh + (size_t)krow * 64 + kc;    // walk +4096/tile
  const bf16* gV = Vh + (size_t)krow * Seq + kc;   // walk +64/tile
  bf16* ldsD = &KV[0][0] + tid * 8;                // K dest; V dest +4096; buf1 +8192

  bf16x8 qf0 = *(const bf16x8*)&Qh[(size_t)(q0 + lr) * 64 + lg * 8];
  bf16x8 qf1 = *(const bf16x8*)&Qh[(size_t)(q0 + lr) * 64 + 32 + lg * 8];

  f32x4 oa[4] = {};
  f32x4 ol = {};                     // ol[j] = running row-sum l for q = q0+4lg+j
  float m = -1e30f;
  bf16x8 ones;
#pragma unroll
  for (int i = 0; i < 8; ++i) ones[i] = (bf16)1.0f;

  auto TILE = [&](int buf) {   // buf is a literal at every call site
    const int kB = buf * 8192;
    // S^T = K Q'^T
    f32x4 st[4] = {};
#pragma unroll
    for (int c = 0; c < 4; ++c) {
      bf16x8 kf0 = *(const bf16x8*)&kv[kb0 + kB + c * 1024];
      bf16x8 kf1 = *(const bf16x8*)&kv[kb1 + kB + c * 1024];
      st[c] = MFMA16(kf0, qf0, st[c]);
      st[c] = MFMA16(kf1, qf1, st[c]);
    }
    // online softmax: max3 tree + 2 shuffles; defer-max THR=3 (exp2 domain)
    float m0 = max3f(st[0][0], st[0][1], st[0][2]);
    float m1 = max3f(st[0][3], st[1][0], st[1][1]);
    float m2 = max3f(st[1][2], st[1][3], st[2][0]);
    float m3 = max3f(st[2][1], st[2][2], st[2][3]);
    float m4 = max3f(st[3][0], st[3][1], st[3][2]);
    float mx = max3f(max3f(m0, m1, m2), m3, fmaxf(m4, st[3][3]));
    mx = fmaxf(mx, __shfl_xor(mx, 16));
    mx = fmaxf(mx, __shfl_xor(mx, 32));
    if (__any(mx > m + 3.0f)) {
      const float mn = fmaxf(m, mx);
      const float al = exp2f(m - mn);
      m = mn;
#pragma unroll
      for (int j = 0; j < 4; ++j) {
        const float aj = __shfl(al, lg * 4 + j);
        ol[j] *= aj;
#pragma unroll
        for (int n = 0; n < 4; ++n) oa[n][j] *= aj;
      }
    }
#pragma unroll
    for (int c = 0; c < 4; ++c) {
      bf16x4 pk;
#pragma unroll
      for (int j = 0; j < 4; ++j) pk[j] = (bf16)exp2f(st[c][j] - m);
      *(bf16x4*)&pw[c * 16] = pk;          // imm offset c*32 bytes
    }
    // PV + ones-MFMA row-sum
    bf16x8 pf0 = *(const bf16x8*)&pr[0];
    bf16x8 pf1 = *(const bf16x8*)&pr[32];
    ol = MFMA16(pf0, ones, ol);
    ol = MFMA16(pf1, ones, ol);
#pragma unroll
    for (int n = 0; n < 4; ++n) {
      bf16x8 vf0 = *(const bf16x8*)&kv[kb0 + kB + 4096 + n * 1024];
      bf16x8 vf1 = *(const bf16x8*)&kv[kb1 + kB + 4096 + n * 1024];
      oa[n] = MFMA16(pf0, vf0, oa[n]);
      oa[n] = MFMA16(pf1, vf1, oa[n]);
    }
  };

  // prologue: stage tile 0 into buf0
  g2l_16(ldsD,        gK);
  g2l_16(ldsD + 4096, gV);
  gK += 4096; gV += 64;
  asm volatile("s_waitcnt vmcnt(0)" ::: "memory");
  __syncthreads();

  for (int it = 0; it < 16; ++it) {
    // stage odd tile into buf1
    g2l_16(ldsD + 8192,        gK);
    g2l_16(ldsD + 8192 + 4096, gV);
    gK += 4096; gV += 64;
    TILE(0);
    asm volatile("s_waitcnt vmcnt(0)" ::: "memory");
    __syncthreads();
    if (it < 15) {   // stage even tile into buf0
      g2l_16(ldsD,        gK);
      g2l_16(ldsD + 4096, gV);
      gK += 4096; gV += 64;
    }
    TILE(1);
    asm volatile("s_waitcnt vmcnt(0)" ::: "memory");
    __syncthreads();
  }

  // epilogue: normalize (l held in-lane), write [B*S, 512] bf16
#pragma unroll
  for (int j = 0; j < 4; ++j) {
    const float lj = 1.0f / ol[j];
    const int s2 = q0 + lg * 4 + j;
#pragma unroll
    for (int n = 0; n < 4; ++n)
      A2[(size_t)(b * Seq + s2) * 512 + h * 64 + n * 16 + lr] = (bf16)(oa[n][j] * lj);
  }
}

extern "C" void kernel_launch(void* const* d_in, const int* in_sizes, int n_in,
                              void* d_out, int out_size, void* d_ws, size_t ws_size,
                              hipStream_t stream) {
  const float* x    = (const float*)d_in[0];
  const float* gam  = (const float*)d_in[1];
  const float* bet  = (const float*)d_in[2];
  const float* wqkv = (const float*)d_in[3];  // [512][1536]
  const float* wout = (const float*)d_in[4];  // [512][512]
  const float* bout = (const float*)d_in[5];  // [512]
  float* out = (float*)d_out;

  bf16* xn    = (bf16*)d_ws;                        // [8192][512]   8 MB
  bf16* wqkvT = xn    + (size_t)8192 * 512;         // [1536][512]   1.5 MB
  bf16* woutT = wqkvT + (size_t)1536 * 512;         // [512][512]    0.5 MB
  bf16* Qb    = woutT + (size_t)512 * 512;          // [4,8,2048,64] 8 MB
  bf16* Kb    = Qb    + (size_t)4 * 8 * 2048 * 64;
  bf16* VT    = Kb    + (size_t)4 * 8 * 2048 * 64;  // [4,8,64,2048] 8 MB
  bf16* A2    = xn;  // reuse: xn dead after QKV GEMM

  // 64^-0.5 * log2(e) folded into Q columns of w_qkv
  const float K1 = 0.18033688011112042f;

  ln_cast_kernel<<<2048, 256, 0, stream>>>(x, gam, bet, xn);
  tcast_kernel<<<dim3(48, 16), 256, 0, stream>>>(wqkv, wqkvT, 512, 1536, 512, K1);
  tcast_kernel<<<dim3(16, 16), 256, 0, stream>>>(wout, woutT, 512, 512, 0, 1.0f);
  gemm_qkv_kernel<<<dim3(64, 12), 256, 0, stream>>>(xn, wqkvT, Qb, Kb, VT);
  attn5_kernel<<<dim3(16, 32), 512, 0, stream>>>(Qb, Kb, VT, A2);
  gemm_out_kernel<<<dim3(64, 4), 256, 0, stream>>>(A2, woutT, bout, out);
}